// Round 4
// baseline (443.587 us; speedup 1.0000x reference)
//
#include <hip/hip_runtime.h>

// HashRouter: h = x @ W^T + b (T x 64), c0/c1 = popcount of sign bits of the
// two 32-output groups; i0 = c0, i1 = c1 + (c1==c0).
// Outputs (float32, concat): weights[T][2]=0.5, indices[T][2], logits[T][64]=0.
//
// R4 restructure: lane j owns output j (NJ == wavefront size).
//  - w[j][k] chunk in lane-j VGPRs via LDS-transposed staging (ds_read_b64,
//    stride-2 lanes -> 2-way -> free). ~8x less LDS pipe than R3.
//  - x[t][k] is wave-uniform -> s_load into SGPRs; inner FMA is
//    v_fmac(acc, s_x, v_w): no LDS/VMEM in the hot loop for x.
//  - h[t][j] in lane j -> __ballot(h>0) gives both 32-bit groups directly.
//  - TBLK=16, 4 waves split K 4-ways, grid 1024 = 4 blocks/CU (16 waves/CU).

constexpr int H_DIM = 2048;
constexpr int NJ    = 64;
constexpr int TBLK  = 16;            // tokens per block
constexpr int KC    = 64;            // k per staged chunk
constexpr int NCH   = H_DIM / KC;    // 32
constexpr int LSTR  = 130;           // float-words per k2 row (64*2 + 2 pad)
constexpr int BUFW  = (KC / 2) * LSTR;   // 4160 words per buffer

__global__ __launch_bounds__(256, 4) void hash_router_kernel(
    const float* __restrict__ x,   // [T, H]
    const float* __restrict__ w,   // [64, H]
    const float* __restrict__ b,   // [64]
    float* __restrict__ out,       // [2T | 2T | 64T]
    int T)
{
    __shared__ float smem[2 * BUFW];               // 33,280 B

    const int tid  = threadIdx.x;
    const int lane = tid & 63;                     // output j
    const int q    = __builtin_amdgcn_readfirstlane(tid >> 6);  // K-quarter
    const int tok0 = blockIdx.x * TBLK;

    float acc[TBLK];
#pragma unroll
    for (int t = 0; t < TBLK; ++t) acc[t] = 0.f;

    // ---- staging registers (flat arrays, no lambdas: avoid R2's spill) ----
    float4 stg[4];
#pragma unroll
    for (int it = 0; it < 4; ++it) {
        const int slot = it * 256 + tid;           // 1024 slots = 64 rows x 16
        const int row = slot >> 4, c4 = slot & 15;
        stg[it] = *(const float4*)(w + (size_t)row * H_DIM + c4 * 4);
    }

    for (int ch = 0; ch < NCH; ++ch) {
        const int fb = (ch & 1) * BUFW;
        // write chunk ch transposed: LDS[k2][j] = (w[j][2k2], w[j][2k2+1])
#pragma unroll
        for (int it = 0; it < 4; ++it) {
            const int slot = it * 256 + tid;
            const int row = slot >> 4, c4 = slot & 15;
            *(float2*)(smem + fb + (c4 * 2)     * LSTR + row * 2) = make_float2(stg[it].x, stg[it].y);
            *(float2*)(smem + fb + (c4 * 2 + 1) * LSTR + row * 2) = make_float2(stg[it].z, stg[it].w);
        }
        if (ch + 1 < NCH) {                        // global prefetch chunk ch+1
#pragma unroll
            for (int it = 0; it < 4; ++it) {
                const int slot = it * 256 + tid;
                const int row = slot >> 4, c4 = slot & 15;
                stg[it] = *(const float4*)(w + (size_t)row * H_DIM + (ch + 1) * KC + c4 * 4);
            }
        }
        __syncthreads();   // chunk ch visible; dbuf makes one barrier enough

        // lane j's w[j][ch*64 + q*16 .. +15] from LDS (stride-2 lanes: free)
        float wr[16];
#pragma unroll
        for (int k2 = 0; k2 < 8; ++k2) {
            const float2 p = *(const float2*)(smem + fb + (q * 8 + k2) * LSTR + lane * 2);
            wr[2 * k2]     = p.x;
            wr[2 * k2 + 1] = p.y;
        }

        // x values are wave-uniform -> s_load; FMA = v_fmac(acc, s_x, v_w)
        const float* xb = x + (size_t)tok0 * H_DIM + ch * KC + q * 16;
#pragma unroll
        for (int t = 0; t < TBLK; ++t) {
            const float4 a0 = *(const float4*)(xb + (size_t)t * H_DIM);
            const float4 a1 = *(const float4*)(xb + (size_t)t * H_DIM + 4);
            const float4 a2 = *(const float4*)(xb + (size_t)t * H_DIM + 8);
            const float4 a3 = *(const float4*)(xb + (size_t)t * H_DIM + 12);
            acc[t] += a0.x * wr[0];  acc[t] += a0.y * wr[1];
            acc[t] += a0.z * wr[2];  acc[t] += a0.w * wr[3];
            acc[t] += a1.x * wr[4];  acc[t] += a1.y * wr[5];
            acc[t] += a1.z * wr[6];  acc[t] += a1.w * wr[7];
            acc[t] += a2.x * wr[8];  acc[t] += a2.y * wr[9];
            acc[t] += a2.z * wr[10]; acc[t] += a2.w * wr[11];
            acc[t] += a3.x * wr[12]; acc[t] += a3.y * wr[13];
            acc[t] += a3.z * wr[14]; acc[t] += a3.w * wr[15];
        }
    }

    // ---- combine K-quarters: waves 1..3 dump partials, wave 0 sums ----
    __syncthreads();                   // all chunk compute done
    if (q) {
#pragma unroll
        for (int t = 0; t < TBLK; ++t)
            smem[(q - 1) * (TBLK * 64) + t * 64 + lane] = acc[t];   // coalesced
    }
    __syncthreads();

    if (q == 0) {
        const float bias = b[lane];
        int myc0 = 0, myc1 = 0;
#pragma unroll
        for (int t = 0; t < TBLK; ++t) {
            float s = acc[t];
            s += smem[0 * (TBLK * 64) + t * 64 + lane];
            s += smem[1 * (TBLK * 64) + t * 64 + lane];
            s += smem[2 * (TBLK * 64) + t * 64 + lane];
            const float v = s + bias;
            bool pos;
            // |h| within fp32 noise of 0 -> exact fp64 recheck (rare)
            if (__builtin_expect(fabsf(v) < 5e-5f, 0)) {
                const float* xr = x + (size_t)(tok0 + t) * H_DIM;
                const float* wr2 = w + (size_t)lane * H_DIM;
                double sd = (double)bias;
                for (int k = 0; k < H_DIM; ++k)
                    sd += (double)xr[k] * (double)wr2[k];
                pos = (sd > 0.0);
            } else {
                pos = (v > 0.0f);
            }
            const unsigned long long m = __ballot(pos);   // bit i = output i
            if (lane == t) {
                myc0 = __popcll(m & 0xffffffffull);
                myc1 = __popcll(m >> 32);
            }
        }
        if (lane < TBLK) {
            const int t = tok0 + lane;
            const int i1 = myc1 + ((myc1 == myc0) ? 1 : 0);
            float2 wq; wq.x = 0.5f; wq.y = 0.5f;
            *(float2*)(out + 2 * (size_t)t) = wq;
            float2 iq; iq.x = (float)myc0; iq.y = (float)i1;
            *(float2*)(out + 2 * (size_t)T + 2 * (size_t)t) = iq;
        }
    }

    // router_logits = 0 (d_out re-poisoned 0xAA before every timed launch)
    float4 z; z.x = 0.f; z.y = 0.f; z.z = 0.f; z.w = 0.f;
    *(float4*)(out + 4 * (size_t)T + (size_t)tok0 * NJ + tid * 4) = z;
}

extern "C" void kernel_launch(void* const* d_in, const int* in_sizes, int n_in,
                              void* d_out, int out_size, void* d_ws, size_t ws_size,
                              hipStream_t stream) {
    const float* x = (const float*)d_in[0];
    const float* w = (const float*)d_in[1];
    const float* b = (const float*)d_in[2];
    float* out = (float*)d_out;
    const int T = in_sizes[0] / H_DIM;      // 16384
    const int grid = T / TBLK;              // 1024
    hash_router_kernel<<<dim3(grid), dim3(256), 0, stream>>>(x, w, b, out, T);
}

// Round 5
// 329.408 us; speedup vs baseline: 1.3466x; 1.3466x over previous
//
#include <hip/hip_runtime.h>

// HashRouter: h = x @ W^T + b (16384 x 64, K=2048), c0/c1 = popcount of sign
// bits of the two 32-output groups; i0 = c0, i1 = c1 + (c1==c0).
// Outputs (float32, concat): weights[T][2]=0.5, indices[T][2], logits[T][64]=0.
//
// R5: split-bf16 MFMA. x = xh + xl, w = wh + wl (bf16 RNE); h = xh*wh + xl*wh
// + xh*wl via mfma_f32_16x16x32_bf16 (fp32 acc). Split error ~5e-6 << the
// 5e-5 fp64-recheck window, so sign-exactness logic is unchanged from the
// passing rounds. MFMA cost ~4 us -> kernel is HBM-bound (134 MB x, ~22 us).
//  - pre-kernel converts w -> wh/wl bf16 in d_ws (L2-resident, reused by all)
//  - main: 256 blocks x 512 thr (1/CU, 8 waves), 64 tok/block; x staged
//    fp32->bf16 hi/lo into dbuf LDS (KC=128, ONE barrier/chunk, register
//    prefetch keeps ~32 KB/CU of HBM loads in flight)
//  - wave = 16 tok x 32 outs: A-frag from LDS (row stride 136 shorts -> 2-way
//    banks, free), B-frags straight from ws (L1-hit), 3 MFMAs/(kstep,ntile)
//  - epilogue: C layout col=lane&15,row=quad*4+reg (m89-verified) -> __ballot
//    -> popcount; rare |h|<5e-5 values get exact fp64 sign (matches np).

typedef __attribute__((ext_vector_type(8))) short short8;
typedef __attribute__((ext_vector_type(4))) float f32x4;

constexpr int H    = 2048;
constexpr int NJ   = 64;
constexpr int TOKB = 64;           // tokens per block
constexpr int KC   = 128;          // k per staged chunk
constexpr int NCH  = H / KC;       // 16
constexpr int RS   = 136;          // LDS row stride in shorts (272 B, 16B-aligned, banks 2-way)
constexpr int PL   = TOKB * RS;    // shorts per plane (hi or lo) = 8704

__device__ __forceinline__ unsigned short bf16_rne(float f) {
    unsigned u = __float_as_uint(f);
    u += 0x7fffu + ((u >> 16) & 1u);
    return (unsigned short)(u >> 16);
}
__device__ __forceinline__ void split1(float f, unsigned short& h, unsigned short& l) {
    h = bf16_rne(f);
    const float hf = __uint_as_float((unsigned)h << 16);
    l = bf16_rne(f - hf);
}

__global__ __launch_bounds__(256) void wcvt_kernel(
    const float* __restrict__ w, unsigned short* __restrict__ wh,
    unsigned short* __restrict__ wl) {
    const int i = (blockIdx.x * 256 + threadIdx.x) * 4;   // 128 blocks cover 64*2048
    const float4 v = *(const float4*)(w + i);
    ushort4 h, l;
    split1(v.x, h.x, l.x); split1(v.y, h.y, l.y);
    split1(v.z, h.z, l.z); split1(v.w, h.w, l.w);
    *(ushort4*)(wh + i) = h;
    *(ushort4*)(wl + i) = l;
}

__global__ __launch_bounds__(512, 2) void hash_router_kernel(
    const float* __restrict__ x,              // [T, H] fp32
    const float* __restrict__ w,              // [64, H] fp32 (recheck only)
    const float* __restrict__ b,              // [64]
    const unsigned short* __restrict__ wh,    // [64, H] bf16 hi
    const unsigned short* __restrict__ wl,    // [64, H] bf16 lo
    float* __restrict__ out,                  // [2T | 2T | 64T]
    int T)
{
    __shared__ unsigned short smem[2 * 2 * PL];   // dbuf x (hi|lo planes), 69632 B
    __shared__ int cnt[TOKB][2];

    const int tid  = threadIdx.x;
    const int lane = tid & 63;
    const int wv   = tid >> 6;        // 0..7
    const int tg   = wv & 3;          // token group: tokens tg*16..+15
    const int nh   = wv >> 1 & 2 ? 0 : 0; // (placeholder removed below)
    (void)nh;
    const int nhalf = wv >> 2;        // 0: outputs 0..31, 1: outputs 32..63
    const int tok0 = blockIdx.x * TOKB;
    const int l15  = lane & 15;
    const int quad = lane >> 4;

    f32x4 acc[2] = {{0.f, 0.f, 0.f, 0.f}, {0.f, 0.f, 0.f, 0.f}};

    // ---- register prefetch of chunk 0 (flat array: no lambda, no spill) ----
    float4 stg[4];
#pragma unroll
    for (int it = 0; it < 4; ++it) {
        const int s = it * 512 + tid;                 // 2048 float4 = 64x128 fp32
        const int row = s >> 5, c4 = s & 31;
        stg[it] = *(const float4*)(x + (size_t)(tok0 + row) * H + c4 * 4);
    }

    for (int ch = 0; ch < NCH; ++ch) {
        const int bb = (ch & 1) * 2 * PL;
        // convert staged chunk ch -> LDS (hi plane, lo plane)
#pragma unroll
        for (int it = 0; it < 4; ++it) {
            const int s = it * 512 + tid;
            const int row = s >> 5, c4 = s & 31;
            const float4 v = stg[it];
            ushort4 h, l;
            split1(v.x, h.x, l.x); split1(v.y, h.y, l.y);
            split1(v.z, h.z, l.z); split1(v.w, h.w, l.w);
            *(ushort4*)(smem + bb + row * RS + c4 * 4)      = h;
            *(ushort4*)(smem + bb + PL + row * RS + c4 * 4) = l;
        }
        // issue chunk ch+1 loads now; they fly across the barrier + compute
        if (ch + 1 < NCH) {
#pragma unroll
            for (int it = 0; it < 4; ++it) {
                const int s = it * 512 + tid;
                const int row = s >> 5, c4 = s & 31;
                stg[it] = *(const float4*)(x + (size_t)(tok0 + row) * H + (ch + 1) * KC + c4 * 4);
            }
        }
        __syncthreads();   // single barrier: dbuf + (convert happens pre-barrier)

        const unsigned short* ab = smem + bb + (tg * 16 + l15) * RS + quad * 8;
#pragma unroll
        for (int ks = 0; ks < 4; ++ks) {
            const short8 ah = *(const short8*)(ab + ks * 32);
            const short8 al = *(const short8*)(ab + PL + ks * 32);
#pragma unroll
            for (int nt = 0; nt < 2; ++nt) {
                const size_t wo = (size_t)(nhalf * 32 + nt * 16 + l15) * H + ch * KC + ks * 32 + quad * 8;
                const short8 bh = *(const short8*)(wh + wo);
                const short8 bl = *(const short8*)(wl + wo);
                acc[nt] = __builtin_amdgcn_mfma_f32_16x16x32_bf16(ah, bh, acc[nt], 0, 0, 0);
                acc[nt] = __builtin_amdgcn_mfma_f32_16x16x32_bf16(al, bh, acc[nt], 0, 0, 0);
                acc[nt] = __builtin_amdgcn_mfma_f32_16x16x32_bf16(ah, bl, acc[nt], 0, 0, 0);
            }
        }
    }

    // ---- epilogue: signs -> ballots -> per-token popcounts ----
    float bias[2];
#pragma unroll
    for (int nt = 0; nt < 2; ++nt) bias[nt] = b[nhalf * 32 + nt * 16 + l15];

    bool pos[2][4];
#pragma unroll
    for (int nt = 0; nt < 2; ++nt)
#pragma unroll
        for (int r = 0; r < 4; ++r) {
            const float v = acc[nt][r] + bias[nt];
            bool p;
            // |h| within split+accum noise of 0 -> exact fp64 sign (rare,
            // ~100 values GPU-wide; same policy as all passing rounds)
            if (__builtin_expect(fabsf(v) < 5e-5f, 0)) {
                const int t = tok0 + tg * 16 + quad * 4 + r;
                const int j = nhalf * 32 + nt * 16 + l15;
                const float* xr = x + (size_t)t * H;
                const float* wr = w + (size_t)j * H;
                double sd = (double)bias[nt];
                for (int k = 0; k < H; ++k)
                    sd += (double)xr[k] * (double)wr[k];
                p = (sd > 0.0);
            } else {
                p = (v > 0.0f);
            }
            pos[nt][r] = p;
        }

    unsigned long long m0[4], m1[4];
#pragma unroll
    for (int r = 0; r < 4; ++r) m0[r] = __ballot(pos[0][r]);
#pragma unroll
    for (int r = 0; r < 4; ++r) m1[r] = __ballot(pos[1][r]);

    // lane L<16 summarizes token tg*16+L of this wave's 32 outputs:
    // ballot bit i (i = q*16 + col) is h[token q*4+r][nhalf*32 + nt*16 + col]
    if (lane < 16) {
        const int q = lane >> 2, rr = lane & 3;
        const int c = __popcll((m0[rr] >> (q * 16)) & 0xffffull)
                    + __popcll((m1[rr] >> (q * 16)) & 0xffffull);
        cnt[tg * 16 + lane][nhalf] = c;
    }
    __syncthreads();

    if (tid < TOKB) {
        const int t  = tok0 + tid;
        const int c0 = cnt[tid][0];
        const int c1 = cnt[tid][1];
        const int i1 = c1 + ((c1 == c0) ? 1 : 0);
        float2 wq; wq.x = 0.5f; wq.y = 0.5f;
        *(float2*)(out + 2 * (size_t)t) = wq;
        float2 iq; iq.x = (float)c0; iq.y = (float)i1;
        *(float2*)(out + 2 * (size_t)T + 2 * (size_t)t) = iq;
    }

    // router_logits = 0 (d_out re-poisoned 0xAA before every timed launch)
    float4 z; z.x = 0.f; z.y = 0.f; z.z = 0.f; z.w = 0.f;
    float* lbase = out + 4 * (size_t)T + (size_t)tok0 * NJ;
    *(float4*)(lbase + tid * 4) = z;
    *(float4*)(lbase + (tid + 512) * 4) = z;
}

extern "C" void kernel_launch(void* const* d_in, const int* in_sizes, int n_in,
                              void* d_out, int out_size, void* d_ws, size_t ws_size,
                              hipStream_t stream) {
    const float* x = (const float*)d_in[0];
    const float* w = (const float*)d_in[1];
    const float* b = (const float*)d_in[2];
    float* out = (float*)d_out;
    const int T = in_sizes[0] / H;                     // 16384
    unsigned short* wh = (unsigned short*)d_ws;        // 64*2048 bf16
    unsigned short* wl = wh + NJ * H;

    wcvt_kernel<<<dim3(NJ * H / 1024), dim3(256), 0, stream>>>(w, wh, wl);
    hash_router_kernel<<<dim3(T / TOKB), dim3(512), 0, stream>>>(
        x, w, b, wh, wl, out, T);
}

// Round 6
// 308.280 us; speedup vs baseline: 1.4389x; 1.0685x over previous
//
#include <hip/hip_runtime.h>

// HashRouter: h = x @ W^T + b (16384 x 64, K=2048), c0/c1 = popcount of sign
// bits of the two 32-output groups; i0 = c0, i1 = c1 + (c1==c0).
// Outputs (float32, concat): weights[T][2]=0.5, indices[T][2], logits[T][64]=0.
//
// R6: barrier-free per-wave MFMA GEMV. R5's stall was the vmcnt(0) drain
// __syncthreads() forces before s_barrier (every chunk serialized HBM latency
// at 1 block/CU). Fix: no LDS staging at all. A-frags (16x16x32 layout:
// lane row=l15, cols quad*8..+7) load straight from global x as 2 coalesced
// float4/lane and split to bf16 hi/lo in registers; B-frags straight from
// wh/wl (512 KB, L2-resident). Split-bf16 numerics identical to R5 (passed):
// h = xh*wh + xl*wh + xh*wl, err ~1e-6 << 5e-5 fp64-recheck window.
// Wave = 16 tok x 64 out x K/4; block = 4 waves (K-quarters) + ONE final
// LDS reduce barrier. Grid 1024 = 4 blocks/CU, 16 waves/CU.

typedef __attribute__((ext_vector_type(8))) short short8;
typedef __attribute__((ext_vector_type(4))) float f32x4;

constexpr int H    = 2048;
constexpr int NJ   = 64;
constexpr int TOKB = 16;            // tokens per block (per wave, K-split)

__device__ __forceinline__ unsigned short bf16_rne(float f) {
    unsigned u = __float_as_uint(f);
    u += 0x7fffu + ((u >> 16) & 1u);
    return (unsigned short)(u >> 16);
}
__device__ __forceinline__ void split1(float f, unsigned short& h, unsigned short& l) {
    h = bf16_rne(f);
    const float hf = __uint_as_float((unsigned)h << 16);
    l = bf16_rne(f - hf);
}

__global__ __launch_bounds__(256) void wcvt_kernel(
    const float* __restrict__ w, unsigned short* __restrict__ wh,
    unsigned short* __restrict__ wl) {
    const int i = (blockIdx.x * 256 + threadIdx.x) * 4;   // 128 blocks cover 64*2048
    const float4 v = *(const float4*)(w + i);
    ushort4 h, l;
    split1(v.x, h.x, l.x); split1(v.y, h.y, l.y);
    split1(v.z, h.z, l.z); split1(v.w, h.w, l.w);
    *(ushort4*)(wh + i) = h;
    *(ushort4*)(wl + i) = l;
}

__global__ __launch_bounds__(256, 4) void hash_router_kernel(
    const float* __restrict__ x,              // [T, H] fp32
    const float* __restrict__ w,              // [64, H] fp32 (recheck only)
    const float* __restrict__ b,              // [64]
    const unsigned short* __restrict__ wh,    // [64, H] bf16 hi
    const unsigned short* __restrict__ wl,    // [64, H] bf16 lo
    float* __restrict__ out,                  // [2T | 2T | 64T]
    int T)
{
    __shared__ float red[3][64][17];          // +1 pad: lane*17 -> 2-way banks

    const int tid  = threadIdx.x;
    const int lane = tid & 63;
    const int q    = __builtin_amdgcn_readfirstlane(tid >> 6);  // K-quarter
    const int l15  = lane & 15;
    const int quad = lane >> 4;
    const int tok0 = blockIdx.x * TOKB;

    f32x4 acc[4] = {{0.f,0.f,0.f,0.f},{0.f,0.f,0.f,0.f},
                    {0.f,0.f,0.f,0.f},{0.f,0.f,0.f,0.f}};

    // Per-lane base pointers (A row = token l15; k-quarter q)
    const float* xbase = x + (size_t)(tok0 + l15) * H + q * 512 + quad * 8;

#pragma unroll 4
    for (int ks = 0; ks < 16; ++ks) {
        const int kb = ks * 32;               // within this wave's K-quarter
        const float4 a0 = *(const float4*)(xbase + kb);
        const float4 a1 = *(const float4*)(xbase + kb + 4);

        short8 ah, al;
        {
            unsigned short h0,l0,h1,l1,h2,l2,h3,l3;
            split1(a0.x,h0,l0); split1(a0.y,h1,l1); split1(a0.z,h2,l2); split1(a0.w,h3,l3);
            ah[0]=(short)h0; ah[1]=(short)h1; ah[2]=(short)h2; ah[3]=(short)h3;
            al[0]=(short)l0; al[1]=(short)l1; al[2]=(short)l2; al[3]=(short)l3;
            split1(a1.x,h0,l0); split1(a1.y,h1,l1); split1(a1.z,h2,l2); split1(a1.w,h3,l3);
            ah[4]=(short)h0; ah[5]=(short)h1; ah[6]=(short)h2; ah[7]=(short)h3;
            al[4]=(short)l0; al[5]=(short)l1; al[6]=(short)l2; al[7]=(short)l3;
        }

#pragma unroll
        for (int nt = 0; nt < 4; ++nt) {
            const size_t wo = (size_t)(nt * 16 + l15) * H + q * 512 + kb + quad * 8;
            const short8 bh = *(const short8*)(wh + wo);
            const short8 bl = *(const short8*)(wl + wo);
            acc[nt] = __builtin_amdgcn_mfma_f32_16x16x32_bf16(ah, bh, acc[nt], 0, 0, 0);
            acc[nt] = __builtin_amdgcn_mfma_f32_16x16x32_bf16(al, bh, acc[nt], 0, 0, 0);
            acc[nt] = __builtin_amdgcn_mfma_f32_16x16x32_bf16(ah, bl, acc[nt], 0, 0, 0);
        }
    }

    // ---- combine K-quarters: waves 1..3 dump, wave 0 sums. ONE barrier. ----
    if (q) {
#pragma unroll
        for (int nt = 0; nt < 4; ++nt)
#pragma unroll
            for (int r = 0; r < 4; ++r)
                red[q - 1][lane][nt * 4 + r] = acc[nt][r];
    }
    __syncthreads();

    if (q == 0) {
#pragma unroll
        for (int i = 0; i < 3; ++i)
#pragma unroll
            for (int nt = 0; nt < 4; ++nt)
#pragma unroll
                for (int r = 0; r < 4; ++r)
                    acc[nt][r] += red[i][lane][nt * 4 + r];

        // C layout (m89): lane(l15,quad), reg r -> token quad*4+r, out nt*16+l15
        bool pos[4][4];
#pragma unroll
        for (int nt = 0; nt < 4; ++nt) {
            const float bias = b[nt * 16 + l15];
#pragma unroll
            for (int r = 0; r < 4; ++r) {
                const float v = acc[nt][r] + bias;
                bool p;
                // |h| within split+accum noise of 0 -> exact fp64 sign (rare)
                if (__builtin_expect(fabsf(v) < 5e-5f, 0)) {
                    const int t = tok0 + quad * 4 + r;
                    const int j = nt * 16 + l15;
                    const float* xr = x + (size_t)t * H;
                    const float* wr = w + (size_t)j * H;
                    double sd = (double)bias;
                    for (int k = 0; k < H; ++k)
                        sd += (double)xr[k] * (double)wr[k];
                    p = (sd > 0.0);
                } else {
                    p = (v > 0.0f);
                }
                pos[nt][r] = p;
            }
        }

        unsigned long long m[4][4];
#pragma unroll
        for (int nt = 0; nt < 4; ++nt)
#pragma unroll
            for (int r = 0; r < 4; ++r)
                m[nt][r] = __ballot(pos[nt][r]);

        // lane L<16 owns token L: quad bits (L>>2)*16, reg (L&3)
        if (lane < 16) {
            const int qq = lane >> 2, rr = lane & 3;
            const int c0 = __popcll((m[0][rr] >> (qq * 16)) & 0xffffull)
                         + __popcll((m[1][rr] >> (qq * 16)) & 0xffffull);
            const int c1 = __popcll((m[2][rr] >> (qq * 16)) & 0xffffull)
                         + __popcll((m[3][rr] >> (qq * 16)) & 0xffffull);
            const int t  = tok0 + lane;
            const int i1 = c1 + ((c1 == c0) ? 1 : 0);
            float2 wq; wq.x = 0.5f; wq.y = 0.5f;
            *(float2*)(out + 2 * (size_t)t) = wq;
            float2 iq; iq.x = (float)c0; iq.y = (float)i1;
            *(float2*)(out + 2 * (size_t)T + 2 * (size_t)t) = iq;
        }
    }

    // router_logits = 0: 16 tok x 64 = 1024 floats = 256 float4, 1/thread
    float4 z; z.x = 0.f; z.y = 0.f; z.z = 0.f; z.w = 0.f;
    *(float4*)(out + 4 * (size_t)T + (size_t)tok0 * NJ + tid * 4) = z;
}

extern "C" void kernel_launch(void* const* d_in, const int* in_sizes, int n_in,
                              void* d_out, int out_size, void* d_ws, size_t ws_size,
                              hipStream_t stream) {
    const float* x = (const float*)d_in[0];
    const float* w = (const float*)d_in[1];
    const float* b = (const float*)d_in[2];
    float* out = (float*)d_out;
    const int T = in_sizes[0] / H;                     // 16384
    unsigned short* wh = (unsigned short*)d_ws;        // 64*2048 bf16
    unsigned short* wl = wh + NJ * H;

    wcvt_kernel<<<dim3(NJ * H / 1024), dim3(256), 0, stream>>>(w, wh, wl);
    hash_router_kernel<<<dim3(T / TOKB), dim3(256), 0, stream>>>(
        x, w, b, wh, wl, out, T);
}

// Round 7
// 302.711 us; speedup vs baseline: 1.4654x; 1.0184x over previous
//
#include <hip/hip_runtime.h>

// HashRouter: h = x @ W^T + b (16384 x 64, K=2048), c0/c1 = popcount of sign
// bits of the two 32-output groups; i0 = c0, i1 = c1 + (c1==c0).
// Outputs (float32, concat): weights[T][2]=0.5, indices[T][2], logits[T][64]=0.
//
// R7: fully-coalesced MFMA with w-in-LDS and K-sliced partials.
//  - k-permutation: MFMA is invariant to a k-slot permutation applied to both
//    A and B. perm(quad,j) = quad*4+j (j<4) / 16+quad*4+j-4 (j>=4) makes each
//    x-load one FULL 64-B line per token row (R6's half-line 16-row gathers
//    were the latency demon: 175 us with all pipes <6%).
//  - w (split-bf16 hi+lo, pre-permuted by wcvt into d_ws) staged ONCE per
//    block into 128 KB LDS; ONE barrier; token loop is barrier-free.
//  - 4 K-slices x 64 blocks = 256 blocks (1/CU), 1024 thr = 16 waves, each
//    wave 16 tokens; fp32 partials to d_ws; reduce kernel sums slices
//    (deterministic), signs w/ 5e-5 fp64-recheck window (same numerics as
//    passing R5/R6), ballots, writes outputs, zeros logits.

typedef __attribute__((ext_vector_type(8))) short short8;
typedef __attribute__((ext_vector_type(4))) float f32x4;

constexpr int H      = 2048;
constexpr int NJ     = 64;
constexpr int T_TOT  = 16384;
constexpr int KSL    = 512;               // K per slice
constexpr int NSL    = 4;
constexpr int NG     = KSL / 32;          // 16 ksteps per slice
constexpr int UNITS_SL = 32 * 64 * 4;     // (g2)(row)(quad) 16-B units = 8192
// d_ws map: wperm [4 slices][8192 units][16 B] = 512 KB, then partials fp32
constexpr size_t WPERM_UNITS = (size_t)NSL * UNITS_SL;          // 32768 units
constexpr size_t PART_OFF    = WPERM_UNITS * 4;                 // in floats

__device__ __forceinline__ unsigned short bf16_rne(float f) {
    unsigned u = __float_as_uint(f);
    u += 0x7fffu + ((u >> 16) & 1u);
    return (unsigned short)(u >> 16);
}
__device__ __forceinline__ void split1(float f, unsigned short& h, unsigned short& l) {
    h = bf16_rne(f);
    const float hf = __uint_as_float((unsigned)h << 16);
    l = bf16_rne(f - hf);
}

// wperm[s][u][row][quad] (u = g*2+plane): 16-B unit holds w[row] cols
// s*512+g*32+perm(quad, j=0..7), plane 0 = bf16-hi, 1 = bf16-lo.
__global__ __launch_bounds__(256) void wcvt_kernel(
    const float* __restrict__ w, unsigned short* __restrict__ wperm) {
    const int n   = blockIdx.x * 256 + threadIdx.x;   // 16384 = 64x16x4x4
    const int quad = n & 3;
    const int g    = (n >> 2) & 15;
    const int s    = (n >> 6) & 3;
    const int row  = n >> 8;
    const float4 a0 = *(const float4*)(w + (size_t)row * H + s * KSL + g * 32 + quad * 4);
    const float4 a1 = *(const float4*)(w + (size_t)row * H + s * KSL + g * 32 + 16 + quad * 4);
    ushort4 h0, l0, h1, l1;
    split1(a0.x, h0.x, l0.x); split1(a0.y, h0.y, l0.y);
    split1(a0.z, h0.z, l0.z); split1(a0.w, h0.w, l0.w);
    split1(a1.x, h1.x, l1.x); split1(a1.y, h1.y, l1.y);
    split1(a1.z, h1.z, l1.z); split1(a1.w, h1.w, l1.w);
    const size_t uh = ((size_t)s * UNITS_SL + (g * 2 + 0) * 256 + row * 4 + quad) * 8;
    const size_t ul = ((size_t)s * UNITS_SL + (g * 2 + 1) * 256 + row * 4 + quad) * 8;
    *(ushort4*)(wperm + uh)     = h0;
    *(ushort4*)(wperm + uh + 4) = h1;
    *(ushort4*)(wperm + ul)     = l0;
    *(ushort4*)(wperm + ul + 4) = l1;
}

__global__ __launch_bounds__(1024, 4) void hash_main_kernel(
    const float* __restrict__ x,                 // [T, H] fp32
    const unsigned short* __restrict__ wperm,    // see wcvt
    float* __restrict__ partials)                // [4][T][64] fp32
{
    __shared__ unsigned short lds[UNITS_SL * 8];   // 128 KB: this block's slice

    const int tid  = threadIdx.x;
    const int s    = __builtin_amdgcn_readfirstlane(blockIdx.x >> 6);
    const int bs   = __builtin_amdgcn_readfirstlane(blockIdx.x & 63);
    const int lane = tid & 63;
    const int wv   = tid >> 6;                   // 0..15: token sub-tile
    const int l15  = lane & 15;
    const int quad = lane >> 4;
    const int t0   = bs * 256 + wv * 16;         // this wave's 16 tokens

    // ---- stage this slice's wperm into LDS (coalesced, bijective) ----
    {
        const float4* src = (const float4*)wperm + (size_t)s * UNITS_SL;
        float4* dst = (float4*)lds;
#pragma unroll
        for (int it = 0; it < 8; ++it) {
            const int u = it * 1024 + tid;
            dst[u] = src[u];
        }
    }
    __syncthreads();     // the only barrier; LDS is read-only afterwards

    f32x4 acc[4] = {{0.f,0.f,0.f,0.f},{0.f,0.f,0.f,0.f},
                    {0.f,0.f,0.f,0.f},{0.f,0.f,0.f,0.f}};

    // per-lane x base: token row t0+l15, k-slice s, quad selects 16-B piece
    const float* xb = x + (size_t)(t0 + l15) * H + s * KSL + quad * 4;

#pragma unroll 2
    for (int g = 0; g < NG; ++g) {
        // a0: cols quad*4..+3 (k-slots j0..3), a1: cols 16+quad*4..+3 (j4..7)
        const float4 a0 = *(const float4*)(xb + g * 32);
        const float4 a1 = *(const float4*)(xb + g * 32 + 16);
        short8 ah, al;
        {
            unsigned short h, l;
            split1(a0.x, h, l); ah[0] = (short)h; al[0] = (short)l;
            split1(a0.y, h, l); ah[1] = (short)h; al[1] = (short)l;
            split1(a0.z, h, l); ah[2] = (short)h; al[2] = (short)l;
            split1(a0.w, h, l); ah[3] = (short)h; al[3] = (short)l;
            split1(a1.x, h, l); ah[4] = (short)h; al[4] = (short)l;
            split1(a1.y, h, l); ah[5] = (short)h; al[5] = (short)l;
            split1(a1.z, h, l); ah[6] = (short)h; al[6] = (short)l;
            split1(a1.w, h, l); ah[7] = (short)h; al[7] = (short)l;
        }
#pragma unroll
        for (int nt = 0; nt < 4; ++nt) {
            // unit (g2, row=nt*16+l15, quad): bijective 1-KB tile, 0 conflicts
            const short8 bh = *(const short8*)(lds + ((g * 2 + 0) * 256 + nt * 64 + l15 * 4 + quad) * 8);
            const short8 bl = *(const short8*)(lds + ((g * 2 + 1) * 256 + nt * 64 + l15 * 4 + quad) * 8);
            acc[nt] = __builtin_amdgcn_mfma_f32_16x16x32_bf16(ah, bh, acc[nt], 0, 0, 0);
            acc[nt] = __builtin_amdgcn_mfma_f32_16x16x32_bf16(al, bh, acc[nt], 0, 0, 0);
            acc[nt] = __builtin_amdgcn_mfma_f32_16x16x32_bf16(ah, bl, acc[nt], 0, 0, 0);
        }
    }

    // C layout (m89, verified R6): reg r -> token quad*4+r, out nt*16+l15
    float* pb = partials + ((size_t)s * T_TOT + t0) * NJ;
#pragma unroll
    for (int nt = 0; nt < 4; ++nt)
#pragma unroll
        for (int r = 0; r < 4; ++r)
            pb[(quad * 4 + r) * NJ + nt * 16 + l15] = acc[nt][r];
}

__global__ __launch_bounds__(256) void hash_reduce_kernel(
    const float* __restrict__ partials,       // [4][T][64]
    const float* __restrict__ x,              // fp64 recheck only
    const float* __restrict__ w,              // fp64 recheck only
    const float* __restrict__ b,
    float* __restrict__ out, int T)
{
    const int tid  = threadIdx.x;
    const int lane = tid & 63;                // = output j
    const int wv   = tid >> 6;
    const int wave_id = blockIdx.x * 4 + wv;  // 1024 waves, 16 tokens each
    const float bias = b[lane];

    for (int i = 0; i < 16; ++i) {
        const int t = wave_id * 16 + i;
        float v = bias;
        v += partials[((size_t)0 * T_TOT + t) * NJ + lane];
        v += partials[((size_t)1 * T_TOT + t) * NJ + lane];
        v += partials[((size_t)2 * T_TOT + t) * NJ + lane];
        v += partials[((size_t)3 * T_TOT + t) * NJ + lane];
        bool pos;
        // |h| within split+accum noise of 0 -> exact fp64 sign (rare)
        if (__builtin_expect(fabsf(v) < 5e-5f, 0)) {
            const float* xr = x + (size_t)t * H;
            const float* wr = w + (size_t)lane * H;
            double sd = (double)bias;
            for (int k = 0; k < H; ++k)
                sd += (double)xr[k] * (double)wr[k];
            pos = (sd > 0.0);
        } else {
            pos = (v > 0.0f);
        }
        const unsigned long long m = __ballot(pos);
        if (lane == 0) {
            const int c0 = __popcll(m & 0xffffffffull);
            const int c1 = __popcll(m >> 32);
            const int i1 = c1 + ((c1 == c0) ? 1 : 0);
            float2 wq; wq.x = 0.5f; wq.y = 0.5f;
            *(float2*)(out + 2 * (size_t)t) = wq;
            float2 iq; iq.x = (float)c0; iq.y = (float)i1;
            *(float2*)(out + 2 * (size_t)T + 2 * (size_t)t) = iq;
        }
    }

    // router_logits = 0 (re-poisoned 0xAA before every timed launch):
    // 4 MB = 262144 float4 over 256 blocks x 256 thr = 4 each
    float4 z; z.x = 0.f; z.y = 0.f; z.z = 0.f; z.w = 0.f;
    float* lbase = out + 4 * (size_t)T;
#pragma unroll
    for (int it = 0; it < 4; ++it)
        *(float4*)(lbase + (size_t)(it * 65536 + blockIdx.x * 256 + tid) * 4) = z;
}

extern "C" void kernel_launch(void* const* d_in, const int* in_sizes, int n_in,
                              void* d_out, int out_size, void* d_ws, size_t ws_size,
                              hipStream_t stream) {
    const float* x = (const float*)d_in[0];
    const float* w = (const float*)d_in[1];
    const float* b = (const float*)d_in[2];
    float* out = (float*)d_out;
    const int T = in_sizes[0] / H;                          // 16384
    unsigned short* wperm = (unsigned short*)d_ws;          // 512 KB
    float* partials = (float*)d_ws + PART_OFF;              // 16 MB fp32

    wcvt_kernel<<<dim3(64), dim3(256), 0, stream>>>(w, wperm);
    hash_main_kernel<<<dim3(256), dim3(1024), 0, stream>>>(x, wperm, partials);
    hash_reduce_kernel<<<dim3(256), dim3(256), 0, stream>>>(partials, x, w, b, out, T);
}